// Round 2
// baseline (10542.773 us; speedup 1.0000x reference)
//
#include <hip/hip_runtime.h>
#include <cstdint>
#include <cstddef>

// Problem dims (fixed by reference setup_inputs)
#define T_STEPS 1000
#define BATCH   64
#define NI_DIM  700
#define NF_DIM  1024
#define NO_DIM  20
#define M_DIM   (T_STEPS * BATCH)   // 64000

// Workspace layout (float offsets)
#define XW_OFF    0ull                          // [64000][1024] = x @ w_in^T
#define WRT_OFF   (XW_OFF + 65536000ull)        // [1024][1024]  w_rec^T (wrT[f'][f] = w_rec[f][f'])
#define WINT_OFF  (WRT_OFF + 1048576ull)        // [700][1024]   w_in^T
#define WOUTT_OFF (WINT_OFF + 716800ull)        // [1024][20]    w_out^T
#define WS_FLOATS (WOUTT_OFF + 20480ull)

// ---------------------------------------------------------------------------
// Tiled transpose: dst[c*R + r] = src[r*C + c]
// ---------------------------------------------------------------------------
__global__ void transpose_k(const float* __restrict__ src, float* __restrict__ dst,
                            int R, int C) {
  __shared__ float tile[32][33];
  int c0 = blockIdx.x * 32, r0 = blockIdx.y * 32;
  int x = threadIdx.x, y = threadIdx.y;  // block (32, 8)
#pragma unroll
  for (int j = 0; j < 32; j += 8) {
    int r = r0 + y + j, c = c0 + x;
    if (r < R && c < C) tile[y + j][x] = src[(size_t)r * C + c];
  }
  __syncthreads();
#pragma unroll
  for (int j = 0; j < 32; j += 8) {
    int r = r0 + x, c = c0 + y + j;
    if (c < C && r < R) dst[(size_t)c * R + r] = tile[x][y + j];
  }
}

// ---------------------------------------------------------------------------
// fp32 GEMM: C[M,N] = A[M,K] * BT[K,N]   (BT = w_in^T, already transposed)
// 128x128 tile, BK=16, 256 threads, 8x8 per thread.
// ---------------------------------------------------------------------------
#define BM 128
#define BN 128
#define BK 16

__global__ __launch_bounds__(256) void gemm_xw(const float* __restrict__ A,
                                               const float* __restrict__ BT,
                                               float* __restrict__ C,
                                               int M, int N, int K) {
  __shared__ float As[BK][BM + 4];
  __shared__ float Bs[BK][BN + 4];
  const int tid = threadIdx.x;
  const int m0 = blockIdx.y * BM;
  const int n0 = blockIdx.x * BN;
  const int tx = tid & 15, ty = tid >> 4;

  float acc[8][8];
#pragma unroll
  for (int i = 0; i < 8; ++i)
#pragma unroll
    for (int j = 0; j < 8; ++j) acc[i][j] = 0.f;

  for (int k0 = 0; k0 < K; k0 += BK) {
    // A tile: 128 rows x 16 k. thread: row = tid>>1, kcol = (tid&1)*8 .. +7
    {
      int ar = tid >> 1;
      int ac = (tid & 1) * 8;
      const float* src = A + (size_t)(m0 + ar) * K + k0 + ac;
#pragma unroll
      for (int j = 0; j < 8; ++j) {
        float v = (k0 + ac + j < K) ? src[j] : 0.f;
        As[ac + j][ar] = v;
      }
    }
    // B tile: 16 k-rows x 128 cols. thread: r = tid>>5 (0..7), c4 = (tid&31)*4; rows r, r+8
    {
      int r = tid >> 5;
      int c4 = (tid & 31) * 4;
#pragma unroll
      for (int rr = 0; rr < 2; ++rr) {
        int k = k0 + r + rr * 8;
        float4 v = make_float4(0.f, 0.f, 0.f, 0.f);
        if (k < K) v = *reinterpret_cast<const float4*>(BT + (size_t)k * N + n0 + c4);
        *reinterpret_cast<float4*>(&Bs[r + rr * 8][c4]) = v;
      }
    }
    __syncthreads();
#pragma unroll
    for (int k = 0; k < BK; ++k) {
      float a[8], b[8];
#pragma unroll
      for (int i = 0; i < 8; ++i) a[i] = As[k][ty * 8 + i];
#pragma unroll
      for (int j = 0; j < 8; ++j) b[j] = Bs[k][tx * 8 + j];
#pragma unroll
      for (int i = 0; i < 8; ++i)
#pragma unroll
        for (int j = 0; j < 8; ++j) acc[i][j] += a[i] * b[j];
    }
    __syncthreads();
  }

#pragma unroll
  for (int i = 0; i < 8; ++i) {
    size_t row = (size_t)(m0 + ty * 8 + i);
    float* cp = C + row * N + n0 + tx * 8;
    float4 v0 = make_float4(acc[i][0], acc[i][1], acc[i][2], acc[i][3]);
    float4 v1 = make_float4(acc[i][4], acc[i][5], acc[i][6], acc[i][7]);
    *reinterpret_cast<float4*>(cp) = v0;
    *reinterpret_cast<float4*>(cp + 4) = v1;
  }
}

// ---------------------------------------------------------------------------
// Sequential LIF recurrence. One workgroup per batch, 1024 threads = neurons.
// Spike list per wave segment (deterministic, no atomics), 1 barrier/step.
// ---------------------------------------------------------------------------
__global__ __launch_bounds__(1024) void lif_seq(const float* __restrict__ XW,
                                                const float* __restrict__ wrT,
                                                const float* __restrict__ w_outT,
                                                float* __restrict__ out) {
#pragma clang fp contract(off)
  const int b = blockIdx.x;
  const int tid = threadIdx.x;       // neuron index f
  const int lane = tid & 63;
  const int wid = tid >> 6;          // 0..15

  __shared__ int   s_list[2][16][64];
  __shared__ int   s_wcnt[2][16];
  __shared__ float s_vo[NO_DIM];

  if (tid < 16) { s_wcnt[0][tid] = 0; s_wcnt[1][tid] = 0; }
  __syncthreads();

  float v = 0.f, cur = 0.f;          // membrane, synaptic current
  float vo = 0.f, io = 0.f;          // readout state (lanes 0..19 only)

  const float* xwp = XW + (size_t)b * NF_DIM + tid;
  const float* wr  = wrT + tid;      // column f of w_rec^T rows

  for (int t = 0; t < T_STEPS; ++t) {
    const int pn = t & 1, po = pn ^ 1;

    float xwv = xwp[(size_t)t * BATCH * NF_DIM];

    // recurrent input: sum of wrT rows over previous step's spike list
    float rec = 0.f;
#pragma unroll 1
    for (int w = 0; w < 16; ++w) {
      int c = s_wcnt[po][w];
      const int* lp = s_list[po][w];
      int k = 0;
      for (; k + 4 <= c; k += 4) {
        float a0 = wr[(size_t)lp[k]     << 10];
        float a1 = wr[(size_t)lp[k + 1] << 10];
        float a2 = wr[(size_t)lp[k + 2] << 10];
        float a3 = wr[(size_t)lp[k + 3] << 10];
        rec += a0; rec += a1; rec += a2; rec += a3;
      }
      for (; k < c; ++k) rec += wr[(size_t)lp[k] << 10];
    }

    // LIF update (mirror numpy rounding: no fma contraction in this kernel)
    float i_dec = cur * 0.8f;
    float v_dec = v + 0.1f * (cur - v);
    bool  z     = v_dec > 1.0f;
    v   = z ? 0.f : v_dec;
    cur = (i_dec + xwv) + rec;

    // build this step's spike list (z_new) into parity pn
    unsigned long long m = __ballot(z);
    if (lane == 0) s_wcnt[pn][wid] = __popcll(m);
    if (z) {
      int pos = __popcll(m & ((1ull << lane) - 1ull));
      s_list[pn][wid][pos] = tid;
    }
    __syncthreads();   // list[pn] complete; old list no longer needed

    // LI readout uses z_new (list[pn])
    if (tid < NO_DIM) {
      float io_dec = io * 0.8f;
      vo = vo + 0.1f * (io - vo);
      float acc = 0.f;
      for (int w = 0; w < 16; ++w) {
        int c = s_wcnt[pn][w];
        const int* lp = s_list[pn][w];
        for (int k = 0; k < c; ++k) acc += w_outT[lp[k] * NO_DIM + tid];
      }
      io = io_dec + acc;
    }
    // no second barrier needed: next iteration writes the opposite parity only
  }

  // log_softmax over NO=20 per batch
  if (tid < NO_DIM) s_vo[tid] = vo;
  __syncthreads();
  if (tid < NO_DIM) {
    float mx = -3.402823466e+38f;
    for (int j = 0; j < NO_DIM; ++j) mx = fmaxf(mx, s_vo[j]);
    float sum = 0.f;
    for (int j = 0; j < NO_DIM; ++j) sum += expf(s_vo[j] - mx);
    out[(size_t)b * NO_DIM + tid] = (vo - mx) - logf(sum);
  }
}

// ---------------------------------------------------------------------------
extern "C" void kernel_launch(void* const* d_in, const int* in_sizes, int n_in,
                              void* d_out, int out_size, void* d_ws, size_t ws_size,
                              hipStream_t stream) {
  const float* x     = (const float*)d_in[0];
  const float* w_in  = (const float*)d_in[1];
  const float* w_rec = (const float*)d_in[2];
  const float* w_out = (const float*)d_in[3];
  float* out = (float*)d_out;
  float* ws  = (float*)d_ws;

  if (ws_size < WS_FLOATS * sizeof(float)) return;  // fail loudly via validation

  float* xw    = ws + XW_OFF;
  float* wrT   = ws + WRT_OFF;
  float* w_inT = ws + WINT_OFF;
  float* w_oT  = ws + WOUTT_OFF;

  // transposes
  {
    dim3 blk(32, 8);
    dim3 g1((NI_DIM + 31) / 32, (NF_DIM + 31) / 32);   // w_in  [1024,700] -> [700,1024]
    transpose_k<<<g1, blk, 0, stream>>>(w_in, w_inT, NF_DIM, NI_DIM);
    dim3 g2((NF_DIM + 31) / 32, (NF_DIM + 31) / 32);   // w_rec [1024,1024] -> wrT
    transpose_k<<<g2, blk, 0, stream>>>(w_rec, wrT, NF_DIM, NF_DIM);
    dim3 g3((NF_DIM + 31) / 32, (NO_DIM + 31) / 32);   // w_out [20,1024] -> [1024,20]
    transpose_k<<<g3, blk, 0, stream>>>(w_out, w_oT, NO_DIM, NF_DIM);
  }

  // XW = x @ w_in^T  : [64000,700] x [700,1024]
  {
    dim3 grid(NF_DIM / BN, M_DIM / BM);  // (8, 500)
    gemm_xw<<<grid, 256, 0, stream>>>(x, w_inT, xw, M_DIM, NF_DIM, NI_DIM);
  }

  // sequential recurrence, one workgroup per batch
  lif_seq<<<BATCH, NF_DIM, 0, stream>>>(xw, wrT, w_oT, out);
}

// Round 3
// 4588.895 us; speedup vs baseline: 2.2975x; 2.2975x over previous
//
#include <hip/hip_runtime.h>
#include <cstdint>
#include <cstddef>

// Problem dims (fixed by reference setup_inputs)
#define T_STEPS 1000
#define BATCH   64
#define NI_DIM  700
#define NF_DIM  1024
#define NO_DIM  20
#define M_DIM   (T_STEPS * BATCH)   // 64000

// Workspace layout (float offsets)
#define XW_OFF    0ull                          // [64000][1024] = x @ w_in^T
#define WRT_OFF   (XW_OFF + 65536000ull)        // [1024][1024]  w_rec^T
#define WINT_OFF  (WRT_OFF + 1048576ull)        // [700][1024]   w_in^T
#define WOUTT_OFF (WINT_OFF + 716800ull)        // [1024][20]    w_out^T
#define WS_FLOATS (WOUTT_OFF + 20480ull)

// ---------------------------------------------------------------------------
// Tiled transpose: dst[c*R + r] = src[r*C + c]
// ---------------------------------------------------------------------------
__global__ void transpose_k(const float* __restrict__ src, float* __restrict__ dst,
                            int R, int C) {
  __shared__ float tile[32][33];
  int c0 = blockIdx.x * 32, r0 = blockIdx.y * 32;
  int x = threadIdx.x, y = threadIdx.y;  // block (32, 8)
#pragma unroll
  for (int j = 0; j < 32; j += 8) {
    int r = r0 + y + j, c = c0 + x;
    if (r < R && c < C) tile[y + j][x] = src[(size_t)r * C + c];
  }
  __syncthreads();
#pragma unroll
  for (int j = 0; j < 32; j += 8) {
    int r = r0 + x, c = c0 + y + j;
    if (c < C && r < R) dst[(size_t)c * R + r] = tile[x][y + j];
  }
}

// ---------------------------------------------------------------------------
// fp32 GEMM: C[M,N] = A[M,K] * BT[K,N]   (BT = w_in^T, already transposed)
// 128x128 tile, BK=16, 256 threads, 8x8 per thread.  (unchanged from R2)
// ---------------------------------------------------------------------------
#define BM 128
#define BN 128
#define BK 16

__global__ __launch_bounds__(256) void gemm_xw(const float* __restrict__ A,
                                               const float* __restrict__ BT,
                                               float* __restrict__ C,
                                               int M, int N, int K) {
  __shared__ float As[BK][BM + 4];
  __shared__ float Bs[BK][BN + 4];
  const int tid = threadIdx.x;
  const int m0 = blockIdx.y * BM;
  const int n0 = blockIdx.x * BN;
  const int tx = tid & 15, ty = tid >> 4;

  float acc[8][8];
#pragma unroll
  for (int i = 0; i < 8; ++i)
#pragma unroll
    for (int j = 0; j < 8; ++j) acc[i][j] = 0.f;

  for (int k0 = 0; k0 < K; k0 += BK) {
    {
      int ar = tid >> 1;
      int ac = (tid & 1) * 8;
      const float* src = A + (size_t)(m0 + ar) * K + k0 + ac;
#pragma unroll
      for (int j = 0; j < 8; ++j) {
        float v = (k0 + ac + j < K) ? src[j] : 0.f;
        As[ac + j][ar] = v;
      }
    }
    {
      int r = tid >> 5;
      int c4 = (tid & 31) * 4;
#pragma unroll
      for (int rr = 0; rr < 2; ++rr) {
        int k = k0 + r + rr * 8;
        float4 v = make_float4(0.f, 0.f, 0.f, 0.f);
        if (k < K) v = *reinterpret_cast<const float4*>(BT + (size_t)k * N + n0 + c4);
        *reinterpret_cast<float4*>(&Bs[r + rr * 8][c4]) = v;
      }
    }
    __syncthreads();
#pragma unroll
    for (int k = 0; k < BK; ++k) {
      float a[8], b[8];
#pragma unroll
      for (int i = 0; i < 8; ++i) a[i] = As[k][ty * 8 + i];
#pragma unroll
      for (int j = 0; j < 8; ++j) b[j] = Bs[k][tx * 8 + j];
#pragma unroll
      for (int i = 0; i < 8; ++i)
#pragma unroll
        for (int j = 0; j < 8; ++j) acc[i][j] += a[i] * b[j];
    }
    __syncthreads();
  }

#pragma unroll
  for (int i = 0; i < 8; ++i) {
    size_t row = (size_t)(m0 + ty * 8 + i);
    float* cp = C + row * N + n0 + tx * 8;
    float4 v0 = make_float4(acc[i][0], acc[i][1], acc[i][2], acc[i][3]);
    float4 v1 = make_float4(acc[i][4], acc[i][5], acc[i][6], acc[i][7]);
    *reinterpret_cast<float4*>(cp) = v0;
    *reinterpret_cast<float4*>(cp + 4) = v1;
  }
}

// ---------------------------------------------------------------------------
// Sequential LIF recurrence. One workgroup per batch, 1024 threads = neurons.
// Flat spike list (deterministic, neuron-ascending — bitwise-identical rec
// order vs R2), 16-wide gather unroll, per-wave readout partials.
// ---------------------------------------------------------------------------
__global__ __launch_bounds__(1024) void lif_seq(const float* __restrict__ XW,
                                                const float* __restrict__ wrT,
                                                const float* __restrict__ w_outT,
                                                float* __restrict__ out) {
#pragma clang fp contract(off)
  const int b = blockIdx.x;
  const int tid = threadIdx.x;       // neuron index f
  const int lane = tid & 63;
  const int wid = tid >> 6;          // 0..15

  __shared__ __attribute__((aligned(16))) int s_flat[2][NF_DIM];  // flat spike lists
  __shared__ int   s_wcnt[2][16];
  __shared__ float s_part[2][16][NO_DIM];   // per-wave readout partials
  __shared__ float s_vo[NO_DIM];

  float v = 0.f, cur = 0.f;          // membrane, synaptic current
  float vo = 0.f, io = 0.f;          // readout state (threads 0..19 only)
  int   C = 0;                       // spike count of previous step (register-carried)

  const float* xwp = XW + (size_t)b * NF_DIM + tid;
  const float* wr  = wrT + tid;      // column f of w_rec^T rows

  for (int t = 0; t < T_STEPS; ++t) {
    const int pn = t & 1, po = pn ^ 1;

    float xwv = __builtin_nontemporal_load(xwp + (size_t)t * (BATCH * NF_DIM));

    // ---- recurrent gather over previous step's flat spike list ----
    // Order: ascending neuron index (identical to R2's segmented order).
    const int* fl = s_flat[po];
    float rec = 0.f;
    int k = 0;
    for (; k + 16 <= C; k += 16) {
      int4 i0 = *reinterpret_cast<const int4*>(&fl[k]);
      int4 i1 = *reinterpret_cast<const int4*>(&fl[k + 4]);
      int4 i2 = *reinterpret_cast<const int4*>(&fl[k + 8]);
      int4 i3 = *reinterpret_cast<const int4*>(&fl[k + 12]);
      float v0  = wr[i0.x << 10];
      float v1  = wr[i0.y << 10];
      float v2  = wr[i0.z << 10];
      float v3  = wr[i0.w << 10];
      float v4  = wr[i1.x << 10];
      float v5  = wr[i1.y << 10];
      float v6  = wr[i1.z << 10];
      float v7  = wr[i1.w << 10];
      float v8  = wr[i2.x << 10];
      float v9  = wr[i2.y << 10];
      float v10 = wr[i2.z << 10];
      float v11 = wr[i2.w << 10];
      float v12 = wr[i3.x << 10];
      float v13 = wr[i3.y << 10];
      float v14 = wr[i3.z << 10];
      float v15 = wr[i3.w << 10];
      // strictly sequential adds: preserves ascending-index summation order
      rec += v0;  rec += v1;  rec += v2;  rec += v3;
      rec += v4;  rec += v5;  rec += v6;  rec += v7;
      rec += v8;  rec += v9;  rec += v10; rec += v11;
      rec += v12; rec += v13; rec += v14; rec += v15;
    }
    for (; k < C; ++k) rec += wr[fl[k] << 10];

    // ---- LIF update (bitwise identical to R2; no fma contraction) ----
    float i_dec = cur * 0.8f;
    float v_dec = v + 0.1f * (cur - v);
    bool  z     = v_dec > 1.0f;
    v   = z ? 0.f : v_dec;
    cur = (i_dec + xwv) + rec;

    // ---- publish this step's spikes ----
    unsigned long long m = __ballot(z);
    int pos = __popcll(m & ((1ull << lane) - 1ull));
    if (lane == 0) s_wcnt[pn][wid] = __popcll(m);

    // per-wave readout partials (lanes 0..19; mask m is wave-uniform so the
    // loop trip count is uniform). Feed-forward path — reassociation safe.
    if (lane < NO_DIM) {
      float p = 0.f;
      unsigned long long mm = m;
      while (mm) {
        int bset = __builtin_ctzll(mm);
        mm &= mm - 1;
        p += w_outT[((wid << 6) + bset) * NO_DIM + lane];
      }
      s_part[pn][wid][lane] = p;
    }

    __syncthreads();   // #1: wcnt + partials complete (z, pos live in regs)

    // redundant 16-way prefix over wave counts -> my segment offset + total
    int total = 0, myoff = 0;
#pragma unroll
    for (int w = 0; w < 16; ++w) {
      int c = s_wcnt[pn][w];
      if (w < wid) myoff += c;
      total += c;
    }
    if (z) s_flat[pn][myoff + pos] = tid;
    C = total;                      // next step's gather count (register)

    // readout finish: 16 LDS adds (off the gather critical path)
    if (tid < NO_DIM) {
      float io_dec = io * 0.8f;
      vo = vo + 0.1f * (io - vo);
      float acc = 0.f;
#pragma unroll
      for (int w = 0; w < 16; ++w) acc += s_part[pn][w][tid];
      io = io_dec + acc;
    }

    __syncthreads();   // #2: flat list complete before next step's gather
  }

  // log_softmax over NO=20 per batch
  if (tid < NO_DIM) s_vo[tid] = vo;
  __syncthreads();
  if (tid < NO_DIM) {
    float mx = -3.402823466e+38f;
    for (int j = 0; j < NO_DIM; ++j) mx = fmaxf(mx, s_vo[j]);
    float sum = 0.f;
    for (int j = 0; j < NO_DIM; ++j) sum += expf(s_vo[j] - mx);
    out[(size_t)b * NO_DIM + tid] = (vo - mx) - logf(sum);
  }
}

// ---------------------------------------------------------------------------
extern "C" void kernel_launch(void* const* d_in, const int* in_sizes, int n_in,
                              void* d_out, int out_size, void* d_ws, size_t ws_size,
                              hipStream_t stream) {
  const float* x     = (const float*)d_in[0];
  const float* w_in  = (const float*)d_in[1];
  const float* w_rec = (const float*)d_in[2];
  const float* w_out = (const float*)d_in[3];
  float* out = (float*)d_out;
  float* ws  = (float*)d_ws;

  if (ws_size < WS_FLOATS * sizeof(float)) return;

  float* xw    = ws + XW_OFF;
  float* wrT   = ws + WRT_OFF;
  float* w_inT = ws + WINT_OFF;
  float* w_oT  = ws + WOUTT_OFF;

  // transposes
  {
    dim3 blk(32, 8);
    dim3 g1((NI_DIM + 31) / 32, (NF_DIM + 31) / 32);   // w_in  [1024,700] -> [700,1024]
    transpose_k<<<g1, blk, 0, stream>>>(w_in, w_inT, NF_DIM, NI_DIM);
    dim3 g2((NF_DIM + 31) / 32, (NF_DIM + 31) / 32);   // w_rec [1024,1024] -> wrT
    transpose_k<<<g2, blk, 0, stream>>>(w_rec, wrT, NF_DIM, NF_DIM);
    dim3 g3((NF_DIM + 31) / 32, (NO_DIM + 31) / 32);   // w_out [20,1024] -> [1024,20]
    transpose_k<<<g3, blk, 0, stream>>>(w_out, w_oT, NO_DIM, NF_DIM);
  }

  // XW = x @ w_in^T  : [64000,700] x [700,1024]
  {
    dim3 grid(NF_DIM / BN, M_DIM / BM);  // (8, 500)
    gemm_xw<<<grid, 256, 0, stream>>>(x, w_inT, xw, M_DIM, NF_DIM, NI_DIM);
  }

  // sequential recurrence, one workgroup per batch
  lif_seq<<<BATCH, NF_DIM, 0, stream>>>(xw, wrT, w_oT, out);
}

// Round 5
// 3475.164 us; speedup vs baseline: 3.0337x; 1.3205x over previous
//
#include <hip/hip_runtime.h>
#include <cstdint>
#include <cstddef>

// Problem dims (fixed by reference setup_inputs)
#define T_STEPS 1000
#define BATCH   64
#define NI_DIM  700
#define NF_DIM  1024
#define NO_DIM  20
#define M_DIM   (T_STEPS * BATCH)   // 64000

// Workspace layout (float offsets)
#define XW_OFF    0ull                          // [64000][1024] = x @ w_in^T
#define WRT_OFF   (XW_OFF + 65536000ull)        // [1024][1024]  w_rec^T
#define WINT_OFF  (WRT_OFF + 1048576ull)        // [700][1024]   w_in^T
#define WOUTT_OFF (WINT_OFF + 716800ull)        // [1024][20]    w_out^T
#define FLAGS_OFF (WOUTT_OFF + 20480ull)        // 512 ints
#define WS_FLOATS (FLAGS_OFF + 512ull)

// Fused-kernel geometry
#define REC_WGS  64
#define GBM 128
#define GBN 256
#define GBK 16
#define MT_TILES (M_DIM / GBM)      // 500 (1 m-tile = 2 timesteps x 64 batches)
#define NT_TILES (NF_DIM / GBN)     // 4
#define SMEM_BYTES 25088            // max(gemm 25088, rec 10960)

typedef float vfloat4 __attribute__((ext_vector_type(4)));

// ---------------------------------------------------------------------------
// Tiled transpose: dst[c*R + r] = src[r*C + c]
// ---------------------------------------------------------------------------
__global__ void transpose_k(const float* __restrict__ src, float* __restrict__ dst,
                            int R, int C) {
  __shared__ float tile[32][33];
  int c0 = blockIdx.x * 32, r0 = blockIdx.y * 32;
  int x = threadIdx.x, y = threadIdx.y;  // block (32, 8)
#pragma unroll
  for (int j = 0; j < 32; j += 8) {
    int r = r0 + y + j, c = c0 + x;
    if (r < R && c < C) tile[y + j][x] = src[(size_t)r * C + c];
  }
  __syncthreads();
#pragma unroll
  for (int j = 0; j < 32; j += 8) {
    int r = r0 + x, c = c0 + y + j;
    if (c < C && r < R) dst[(size_t)c * R + r] = tile[x][y + j];
  }
}

__global__ void zero_flags_k(int* __restrict__ flags) {
  if (threadIdx.x < 512) flags[threadIdx.x] = 0;
}

// ---------------------------------------------------------------------------
// Fused kernel. Blocks 0..63: recurrence (1 per batch). Blocks 64..2063:
// GEMM tiles of XW = x @ w_in^T, publishing per-m-tile flags (agent scope).
// ---------------------------------------------------------------------------
__global__ __launch_bounds__(1024) void fused_k(
    const float* __restrict__ x, const float* __restrict__ w_inT,
    float* __restrict__ XW, const float* __restrict__ wrT,
    const float* __restrict__ w_outT, int* __restrict__ flags,
    float* __restrict__ out) {
  __shared__ __attribute__((aligned(16))) char smem[SMEM_BYTES];
  const int tid = threadIdx.x;

  if (blockIdx.x >= REC_WGS) {
    // ------------------------- GEMM producer role -------------------------
    float (*As)[GBM + 4] = reinterpret_cast<float (*)[GBM + 4]>(smem);
    float (*Bs)[GBN + 4] =
        reinterpret_cast<float (*)[GBN + 4]>(smem + GBK * (GBM + 4) * 4);
    const int id = blockIdx.x - REC_WGS;
    const int mt = id >> 2;          // NT_TILES = 4; ascending mt with blockIdx
    const int nt = id & 3;
    const int m0 = mt * GBM, n0 = nt * GBN;
    const int tx = tid & 31, ty = tid >> 5;

    float acc[4][8];
#pragma unroll
    for (int i = 0; i < 4; ++i)
#pragma unroll
      for (int j = 0; j < 8; ++j) acc[i][j] = 0.f;

    for (int k0 = 0; k0 < NI_DIM; k0 += GBK) {
      {  // A tile: 128 rows x 16 k (2 elems/thread), nt loads (don't pollute L2)
        int ar = tid >> 3, ac = (tid & 7) * 2;
        const float* src = x + (size_t)(m0 + ar) * NI_DIM + k0 + ac;
        float v0 = (k0 + ac     < NI_DIM) ? __builtin_nontemporal_load(src)     : 0.f;
        float v1 = (k0 + ac + 1 < NI_DIM) ? __builtin_nontemporal_load(src + 1) : 0.f;
        As[ac][ar] = v0;
        As[ac + 1][ar] = v1;
      }
      {  // B tile: 16 k-rows x 256 cols (float4/thread)
        int r = tid >> 6, c4 = (tid & 63) * 4;
        int kk = k0 + r;
        float4 vv = make_float4(0.f, 0.f, 0.f, 0.f);
        if (kk < NI_DIM)
          vv = *reinterpret_cast<const float4*>(w_inT + (size_t)kk * NF_DIM + n0 + c4);
        *reinterpret_cast<float4*>(&Bs[r][c4]) = vv;
      }
      __syncthreads();
#pragma unroll
      for (int k = 0; k < GBK; ++k) {
        float a[4], b[8];
#pragma unroll
        for (int i = 0; i < 4; ++i) a[i] = As[k][ty * 4 + i];
#pragma unroll
        for (int j = 0; j < 8; ++j) b[j] = Bs[k][tx * 8 + j];
#pragma unroll
        for (int i = 0; i < 4; ++i)
#pragma unroll
          for (int j = 0; j < 8; ++j) acc[i][j] += a[i] * b[j];
      }
      __syncthreads();
    }

#pragma unroll
    for (int i = 0; i < 4; ++i) {
      size_t row = (size_t)(m0 + ty * 4 + i);
      float* cp = XW + row * NF_DIM + n0 + tx * 8;
      vfloat4 v0 = {acc[i][0], acc[i][1], acc[i][2], acc[i][3]};
      vfloat4 v1 = {acc[i][4], acc[i][5], acc[i][6], acc[i][7]};
      __builtin_nontemporal_store(v0, reinterpret_cast<vfloat4*>(cp));
      __builtin_nontemporal_store(v1, reinterpret_cast<vfloat4*>(cp + 4));
    }
    __syncthreads();  // compiler drains vmcnt before barrier -> stores complete
    if (tid == 0)
      __hip_atomic_fetch_add(&flags[mt], 1, __ATOMIC_RELEASE,
                             __HIP_MEMORY_SCOPE_AGENT);
    return;
  }

  // ------------------------- recurrence consumer role -------------------------
  {
#pragma clang fp contract(off)
    int*   s_flat = reinterpret_cast<int*>(smem);           // [2][1024]
    int*   s_wcnt = reinterpret_cast<int*>(smem + 8192);    // [2][16]
    float* s_part = reinterpret_cast<float*>(smem + 8320);  // [2][16][20]
    float* s_vo   = reinterpret_cast<float*>(smem + 10880); // [20]

    const int b = blockIdx.x;
    const int lane = tid & 63, wid = tid >> 6;
    const unsigned tidu = (unsigned)tid;

    float v = 0.f, cur = 0.f;   // membrane, synaptic current
    float vo = 0.f, io = 0.f;   // readout state (threads 0..19)
    int C = 0;                  // previous step's spike count

    const float* xwp = XW + (size_t)b * NF_DIM + tid;

    if (tid == 0) {  // chunk 0 covers t=0,1
      while (__hip_atomic_load(&flags[0], __ATOMIC_RELAXED,
                               __HIP_MEMORY_SCOPE_AGENT) < NT_TILES)
        __builtin_amdgcn_s_sleep(2);
      (void)__hip_atomic_load(&flags[0], __ATOMIC_ACQUIRE,
                              __HIP_MEMORY_SCOPE_AGENT);
    }
    __syncthreads();

    for (int t = 0; t < T_STEPS; ++t) {
      const int pn = t & 1, po = pn ^ 1;
      float xwv = __builtin_nontemporal_load(xwp + (size_t)t * (BATCH * NF_DIM));

      // ---- recurrent gather, ascending neuron order (bitwise == R3) ----
      const int* fl = s_flat + po * NF_DIM;
      float rec = 0.f;
      int kk = 0;
      for (; kk + 32 <= C; kk += 32) {
        int idx[32];
#pragma unroll
        for (int u = 0; u < 8; ++u)
          *reinterpret_cast<int4*>(&idx[u * 4]) =
              *reinterpret_cast<const int4*>(&fl[kk + u * 4]);
        float val[32];
#pragma unroll
        for (int u = 0; u < 32; ++u)
          val[u] = wrT[(((unsigned)idx[u]) << 10) + tidu];
#pragma unroll
        for (int u = 0; u < 32; ++u) rec += val[u];  // sequential: order kept
      }
      for (; kk + 8 <= C; kk += 8) {
        int idx[8];
#pragma unroll
        for (int u = 0; u < 2; ++u)
          *reinterpret_cast<int4*>(&idx[u * 4]) =
              *reinterpret_cast<const int4*>(&fl[kk + u * 4]);
        float val[8];
#pragma unroll
        for (int u = 0; u < 8; ++u)
          val[u] = wrT[(((unsigned)idx[u]) << 10) + tidu];
#pragma unroll
        for (int u = 0; u < 8; ++u) rec += val[u];
      }
      for (; kk < C; ++kk) rec += wrT[(((unsigned)fl[kk]) << 10) + tidu];

      // ---- LIF update (no fma contraction; bitwise == R2/R3) ----
      float i_dec = cur * 0.8f;
      float v_dec = v + 0.1f * (cur - v);
      bool  z     = v_dec > 1.0f;
      v   = z ? 0.f : v_dec;
      cur = (i_dec + xwv) + rec;

      // ---- publish spikes ----
      unsigned long long m = __ballot(z);
      int pos = __popcll(m & ((1ull << lane) - 1ull));
      if (lane == 0) s_wcnt[pn * 16 + wid] = __popcll(m);

      // per-wave readout partials (feed-forward; reassociation safe)
      if (lane < NO_DIM) {
        float p = 0.f;
        unsigned long long mm = m;
        while (mm) {
          int bset = __builtin_ctzll(mm);
          mm &= mm - 1;
          p += w_outT[((wid << 6) + bset) * NO_DIM + lane];
        }
        s_part[(pn * 16 + wid) * NO_DIM + lane] = p;
      }

      __syncthreads();  // #1: wcnt + partials ready

      int total = 0, myoff = 0;
#pragma unroll
      for (int w = 0; w < 16; ++w) {
        int c = s_wcnt[pn * 16 + w];
        if (w < wid) myoff += c;
        total += c;
      }
      if (z) s_flat[pn * NF_DIM + myoff + pos] = tid;
      C = total;

      if (tid < NO_DIM) {
        float io_dec = io * 0.8f;
        vo = vo + 0.1f * (io - vo);
        float acc = 0.f;
#pragma unroll
        for (int w = 0; w < 16; ++w) acc += s_part[(pn * 16 + w) * NO_DIM + tid];
        io = io_dec + acc;
      }

      // piggyback next chunk's flag wait on barrier #2 (thread 0 only)
      if ((t & 1) && (t + 1 < T_STEPS) && tid == 0) {
        const int c = (t + 1) >> 1;
        while (__hip_atomic_load(&flags[c], __ATOMIC_RELAXED,
                                 __HIP_MEMORY_SCOPE_AGENT) < NT_TILES)
          __builtin_amdgcn_s_sleep(2);
        (void)__hip_atomic_load(&flags[c], __ATOMIC_ACQUIRE,
                                __HIP_MEMORY_SCOPE_AGENT);
      }
      __syncthreads();  // #2: flat list complete (and next XW chunk visible)
    }

    // log_softmax over NO=20 per batch
    if (tid < NO_DIM) s_vo[tid] = vo;
    __syncthreads();
    if (tid < NO_DIM) {
      float mx = -3.402823466e+38f;
      for (int j = 0; j < NO_DIM; ++j) mx = fmaxf(mx, s_vo[j]);
      float sum = 0.f;
      for (int j = 0; j < NO_DIM; ++j) sum += expf(s_vo[j] - mx);
      out[(size_t)b * NO_DIM + tid] = (vo - mx) - logf(sum);
    }
  }
}

// ---------------------------------------------------------------------------
extern "C" void kernel_launch(void* const* d_in, const int* in_sizes, int n_in,
                              void* d_out, int out_size, void* d_ws, size_t ws_size,
                              hipStream_t stream) {
  const float* x     = (const float*)d_in[0];
  const float* w_in  = (const float*)d_in[1];
  const float* w_rec = (const float*)d_in[2];
  const float* w_out = (const float*)d_in[3];
  float* out = (float*)d_out;
  float* ws  = (float*)d_ws;

  if (ws_size < WS_FLOATS * sizeof(float)) return;

  float* xw    = ws + XW_OFF;
  float* wrT   = ws + WRT_OFF;
  float* w_inT = ws + WINT_OFF;
  float* w_oT  = ws + WOUTT_OFF;
  int*   flags = (int*)(ws + FLAGS_OFF);

  // transposes + flag reset (dispatch-boundary flush makes them visible)
  {
    dim3 blk(32, 8);
    dim3 g1((NI_DIM + 31) / 32, (NF_DIM + 31) / 32);
    transpose_k<<<g1, blk, 0, stream>>>(w_in, w_inT, NF_DIM, NI_DIM);
    dim3 g2((NF_DIM + 31) / 32, (NF_DIM + 31) / 32);
    transpose_k<<<g2, blk, 0, stream>>>(w_rec, wrT, NF_DIM, NF_DIM);
    dim3 g3((NF_DIM + 31) / 32, (NO_DIM + 31) / 32);
    transpose_k<<<g3, blk, 0, stream>>>(w_out, w_oT, NO_DIM, NF_DIM);
    zero_flags_k<<<1, 512, 0, stream>>>(flags);
  }

  // fused producer-consumer: recurrence WGs first (resident from t=0)
  fused_k<<<REC_WGS + MT_TILES * NT_TILES, 1024, 0, stream>>>(
      x, w_inT, xw, wrT, w_oT, flags, out);
}